// Round 9
// baseline (34.596 us; speedup 1.0000x reference)
//
#include <hip/hip_runtime.h>

// Problem constants (fixed by setup_inputs: B=64, PER=512, N_COMPOUND=112)
constexpr int PERN = 512;
constexpr int NCMP = 112;
constexpr int BATCHES = 64;
constexpr float INTRA_CUT = 1.6f;   // 8.0 / 5.0
constexpr float INTER_CUT = 2.0f;   // 10.0 / 5.0
constexpr int ROWS_PER_BLOCK = 16;  // 32 tiles per batch per plane

typedef float f32x4 __attribute__((ext_vector_type(4)));

// Plane-split: grid = 3 * 2048 blocks, plane-major. Each block computes the
// full pair logic for a 16-row tile but stores ONLY its plane -> each wave
// has exactly ONE monotone store stream (8KB contiguous per pass), and each
// dispatch phase linearly sweeps one 67MB plane (fill-kernel-like pattern).
__global__ __launch_bounds__(256, 8) void pair_mask_kernel(
    const float* __restrict__ X, float* __restrict__ out)
{
    const int tid = threadIdx.x;
    const int blk = blockIdx.x;
    const int plane = blk >> 11;           // 0: ctx, 1: inter, 2: masked_dist
    const int tile = blk & 2047;
    const int b = tile >> 5;               // tile / 32
    const int row0 = (tile & 31) << 4;     // (tile % 32) * 16
    const int lane = tid & 63;
    const int sub = tid >> 6;
    const size_t NP = (size_t)BATCHES * PERN * PERN;  // elements per plane
    const float* Xb = X + (size_t)b * PERN * 3;
    float* oplane = out + (size_t)plane * NP;

    // Load both j-chunks' point coords (AoS [p][3]) coalesced and
    // deinterleave in registers. jbase(c) = c*256 + 4*lane. 96B/lane, reused
    // across all 16 rows.
    f32x4 xv[2], yv[2], zv[2];
#pragma unroll
    for (int c = 0; c < 2; ++c) {
        const int jbase = c * 256 + (lane << 2);
        const f32x4 A = *reinterpret_cast<const f32x4*>(Xb + 3 * jbase);      // x0 y0 z0 x1
        const f32x4 Bv = *reinterpret_cast<const f32x4*>(Xb + 3 * jbase + 4); // y1 z1 x2 y2
        const f32x4 Cv = *reinterpret_cast<const f32x4*>(Xb + 3 * jbase + 8); // z2 x3 y3 z3
        xv[c] = (f32x4){A[0], A[3], Bv[2], Cv[1]};
        yv[c] = (f32x4){A[1], Bv[0], Bv[3], Cv[2]};
        zv[c] = (f32x4){A[2], Bv[1], Cv[0], Cv[3]};
    }

    // Each wave owns 4 CONSECUTIVE rows: its single store stream advances
    // monotonically (4 x 2KB = 8KB contiguous per pass).
#pragma unroll
    for (int pass = 0; pass < ROWS_PER_BLOCK / 4; ++pass) {
        const int li = row0 + sub * 4 + pass;          // local row index
        const float pix = Xb[3 * li + 0];              // wave-uniform (cache hit)
        const float piy = Xb[3 * li + 1];
        const float piz = Xb[3 * li + 2];
        const bool rg = (li == 0) | (li == NCMP);      // row is_global
        const int  sr = (li >= NCMP);                  // row segment
        float* orow = oplane + (size_t)(b * PERN + li) * PERN;

#pragma unroll
        for (int c = 0; c < 2; ++c) {
            const int jbase = c * 256 + (lane << 2);
            f32x4 vvv;
#pragma unroll
            for (int k = 0; k < 4; ++k) {
                const int j = jbase + k;
                const float dx = pix - xv[c][k];
                const float dy = piy - yv[c][k];
                const float dz = piz - zv[c][k];
                const float d2 = dx * dx + dy * dy + dz * dz;
                const bool valid = (j != li);
                const bool fin = valid & (d2 > 0.0f);      // dist finite in ref
                const float dist = __builtin_amdgcn_sqrtf(d2);
                const bool cgl = (j == 0) | (j == NCMP);   // col is_global (raw)
                const bool cg = cgl & valid;
                const bool notg = !(rg | cg);
                const int  sj = (j >= NCMP);
                const bool same = valid & (sr == sj);
                const bool ctxr  = same & (sr == 1) & notg & fin & (dist <= INTRA_CUT);
                const bool inter = valid & (sr != sj) & notg & fin & (dist <= INTER_CUT);
                const bool gnorm = same & (!notg);
                const bool gg    = valid & rg & cgl;
                const bool ctx   = ctxr | gnorm | gg;
                const float ccv = ctx ? 1.0f : 0.0f;
                const float iiv = inter ? 1.0f : 0.0f;
                const float mmv = ((ctx | inter) & fin) ? dist : 0.0f;
                // branch-free plane select (plane is block-uniform)
                vvv[k] = (plane == 0) ? ccv : ((plane == 1) ? iiv : mmv);
            }
            *reinterpret_cast<f32x4*>(orow + jbase) = vvv;  // 64x16B = 1KB burst
        }
    }
}

extern "C" void kernel_launch(void* const* d_in, const int* in_sizes, int n_in,
                              void* d_out, int out_size, void* d_ws, size_t ws_size,
                              hipStream_t stream) {
    const float* X = (const float*)d_in[0];
    float* out = (float*)d_out;
    const int grid = 3 * BATCHES * (PERN / ROWS_PER_BLOCK);  // 6144 blocks
    pair_mask_kernel<<<grid, 256, 0, stream>>>(X, out);
}

// Round 10
// 33.114 us; speedup vs baseline: 1.0448x; 1.0448x over previous
//
#include <hip/hip_runtime.h>

// Problem constants (fixed by setup_inputs: B=64, PER=512, N_COMPOUND=112)
constexpr int PERN = 512;
constexpr int NCMP = 112;
constexpr int BATCHES = 64;
constexpr float INTRA_CUT = 1.6f;   // 8.0 / 5.0
constexpr float INTER_CUT = 2.0f;   // 10.0 / 5.0
constexpr int ROWS_PER_BLOCK = 16;  // 32 blocks per batch

typedef float f32x4 __attribute__((ext_vector_type(4)));

// Best-measured configuration (33.3 us, 6.05 TB/s): cached wave-contiguous
// stores, 3 interleaved plane streams per wave, no LDS, register-resident
// j-side points. nt stores (-23%), plane-split (-4%), LDS staging (null),
// half-line interleave (-17%) all measured worse.
__global__ __launch_bounds__(256, 8) void pair_mask_kernel(
    const float* __restrict__ X, float* __restrict__ out)
{
    const int tid = threadIdx.x;
    const int blk = blockIdx.x;
    const int b = blk / (PERN / ROWS_PER_BLOCK);
    const int row0 = (blk % (PERN / ROWS_PER_BLOCK)) * ROWS_PER_BLOCK;
    const int lane = tid & 63;
    const int sub = tid >> 6;
    const size_t NP = (size_t)BATCHES * PERN * PERN;  // elements per plane
    const float* Xb = X + (size_t)b * PERN * 3;

    // Load both j-chunks' point coords (AoS [p][3]) coalesced and
    // deinterleave in registers. jbase(c) = c*256 + 4*lane.
    f32x4 xv[2], yv[2], zv[2];
#pragma unroll
    for (int c = 0; c < 2; ++c) {
        const int jbase = c * 256 + (lane << 2);
        const f32x4 A = *reinterpret_cast<const f32x4*>(Xb + 3 * jbase);      // x0 y0 z0 x1
        const f32x4 Bv = *reinterpret_cast<const f32x4*>(Xb + 3 * jbase + 4); // y1 z1 x2 y2
        const f32x4 Cv = *reinterpret_cast<const f32x4*>(Xb + 3 * jbase + 8); // z2 x3 y3 z3
        xv[c] = (f32x4){A[0], A[3], Bv[2], Cv[1]};
        yv[c] = (f32x4){A[1], Bv[0], Bv[3], Cv[2]};
        zv[c] = (f32x4){A[2], Bv[1], Cv[0], Cv[3]};
    }

    // Each wave owns 4 CONSECUTIVE rows: store streams advance monotonically
    // in 2KB steps (8KB contiguous per plane per wave).
#pragma unroll
    for (int pass = 0; pass < ROWS_PER_BLOCK / 4; ++pass) {
        const int li = row0 + sub * 4 + pass;          // local row index
        const float pix = Xb[3 * li + 0];              // wave-uniform (cache hit)
        const float piy = Xb[3 * li + 1];
        const float piz = Xb[3 * li + 2];
        const bool rg = (li == 0) | (li == NCMP);      // row is_global
        const int  sr = (li >= NCMP);                  // row segment
        float* orow = out + (size_t)(b * PERN + li) * PERN;

        // Lane owns j = c*256 + 4*lane + k: each f32x4 store is wave-contiguous
        // (64 lanes x 16B = 1KB aligned burst -> full 64B lines, L2 write-back).
#pragma unroll
        for (int c = 0; c < 2; ++c) {
            const int jbase = c * 256 + (lane << 2);
            f32x4 cc, ii, mm;
#pragma unroll
            for (int k = 0; k < 4; ++k) {
                const int j = jbase + k;
                const float dx = pix - xv[c][k];
                const float dy = piy - yv[c][k];
                const float dz = piz - zv[c][k];
                const float d2 = dx * dx + dy * dy + dz * dz;
                const bool valid = (j != li);
                const bool fin = valid & (d2 > 0.0f);      // dist finite in ref
                const float dist = __builtin_amdgcn_sqrtf(d2);
                const bool cgl = (j == 0) | (j == NCMP);   // col is_global (raw)
                const bool cg = cgl & valid;
                const bool notg = !(rg | cg);
                const int  sj = (j >= NCMP);
                const bool same = valid & (sr == sj);
                const bool ctxr  = same & (sr == 1) & notg & fin & (dist <= INTRA_CUT);
                const bool inter = valid & (sr != sj) & notg & fin & (dist <= INTER_CUT);
                const bool gnorm = same & (!notg);
                const bool gg    = valid & rg & cgl;
                const bool ctx   = ctxr | gnorm | gg;
                cc[k] = ctx ? 1.0f : 0.0f;
                ii[k] = inter ? 1.0f : 0.0f;
                mm[k] = ((ctx | inter) & fin) ? dist : 0.0f;
            }
            *reinterpret_cast<f32x4*>(orow + jbase)          = cc;
            *reinterpret_cast<f32x4*>(orow + NP + jbase)     = ii;
            *reinterpret_cast<f32x4*>(orow + 2 * NP + jbase) = mm;
        }
    }
}

extern "C" void kernel_launch(void* const* d_in, const int* in_sizes, int n_in,
                              void* d_out, int out_size, void* d_ws, size_t ws_size,
                              hipStream_t stream) {
    const float* X = (const float*)d_in[0];
    float* out = (float*)d_out;
    const int grid = BATCHES * (PERN / ROWS_PER_BLOCK);  // 2048 blocks
    pair_mask_kernel<<<grid, 256, 0, stream>>>(X, out);
}